// Round 2
// baseline (282.941 us; speedup 1.0000x reference)
//
#include <hip/hip_runtime.h>
#include <math.h>

// Problem constants (match reference)
constexpr int T_LEN = 15360;
constexpr int B_DIM = 64;
constexpr int C_DIM = 64;
constexpr int NTHR  = 256;
constexpr int VPT   = T_LEN / 4 / NTHR;   // 15 float4 / thread (full-row strided)
constexpr int KHALF = 12;                 // k=25 taps -> halo 12
constexpr int CH     = 3072;              // chunk elems (divisible by 1024)
constexpr int NCHUNK = T_LEN / CH;        // 5
constexpr int EPT    = CH / NTHR;         // 12 elems / thread / chunk
constexpr int F4PT   = CH / 4 / NTHR;     // 3 float4 / thread / chunk

__global__ __launch_bounds__(NTHR, 6)
void emg_inject_kernel(const float* __restrict__ x,
                       const float* __restrict__ noise,
                       const float* __restrict__ apply_u,
                       const float* __restrict__ frac_u,
                       const float* __restrict__ ch_u,
                       const float* __restrict__ burst_u,
                       const float* __restrict__ start_u,
                       const float* __restrict__ snr_u,
                       float* __restrict__ out)
{
    const int row = blockIdx.x;          // row = b*C + c
    const int b   = row >> 6;
    const int c   = row & 63;
    const int tid = threadIdx.x;

    __shared__ float s_ch[C_DIM];
    __shared__ float s_red[8];
    __shared__ __align__(16) float s_buf[CH + 2 * KHALF + 1];  // 3097 f -> 12.4 KB

    if (tid < C_DIM) s_ch[tid] = ch_u[(size_t)b * C_DIM + tid];
    __syncthreads();

    // --- channel selection: rank(ch_u[b,c]) < n_aff ---
    const float myv = s_ch[c];
    int rank = 0;
    #pragma unroll 8
    for (int i = 0; i < C_DIM; ++i) {
        float v = s_ch[i];
        rank += (v < myv || (v == myv && i < c)) ? 1 : 0;
    }
    const float frac = frac_u[b];
    int n_aff = (int)floorf(((float)C_DIM * frac) * 0.5f);
    n_aff = max(1, n_aff);
    const bool affected = (apply_u[b] <= 0.4f) && (rank < n_aff);

    const float*  xrow = x   + (size_t)row * T_LEN;
    const float*  nrow = noise + (size_t)row * T_LEN;
    float*        orow = out + (size_t)row * T_LEN;
    const float4* x4   = (const float4*)xrow;
    float4*       o4   = (float4*)orow;

    if (!affected) {
        // pure copy: out = x  (coalesced float4)
        #pragma unroll
        for (int it = 0; it < VPT; ++it) {
            int idx = tid + it * NTHR;
            o4[idx] = x4[idx];
        }
        return;
    }

    // ---------------- affected row ----------------
    // burst mask parameters (block-uniform, f32 math matches reference)
    const float bu   = burst_u[b];
    const float bfr  = 0.1f + bu * 0.4f;
    const int   blen = (int)floorf((float)T_LEN * bfr);
    int tmb = T_LEN - blen; if (tmb < 1) tmb = 1;
    const int   start = (int)floorf(start_u[b] * (float)tmb);
    const int   elen  = min(25, blen / 4);
    const float sf    = (float)start;
    const float endf  = sf + (float)blen;
    const float ef    = (float)elen;
    const float denom = fmaxf(ef - 1.0f, 1.0f);
    const float inv_denom = 1.0f / denom;
    const float head_end  = sf + ef;
    const float tail_beg  = endf - ef;
    const float inv_k = 1.0f / 25.0f;

    // sumx2 over full row (coalesced float4, strided)
    float sumx2 = 0.f;
    #pragma unroll
    for (int it = 0; it < VPT; ++it) {
        float4 xv = x4[tid + it * NTHR];
        sumx2 += xv.x * xv.x + xv.y * xv.y + xv.z * xv.z + xv.w * xv.w;
    }

    // ---- Pass 1: sum(emg_b^2) over chunks ----
    float sume2 = 0.f;
    for (int ck = 0; ck < NCHUNK; ++ck) {
        const int g0 = ck * CH;
        // stage interior (coalesced float4; s_buf+12 is 16B aligned: 48 bytes)
        const float4* nsrc = (const float4*)(nrow + g0);
        float4* sb4 = (float4*)(s_buf + KHALF);
        #pragma unroll
        for (int it = 0; it < F4PT; ++it) {
            int q = tid + it * NTHR;
            sb4[q] = nsrc[q];
        }
        // halos (zero-pad at row edges, matching conv zero padding)
        if (tid < KHALF) {
            int gl = g0 - KHALF + tid;
            s_buf[tid] = (gl >= 0) ? nrow[gl] : 0.f;
            int gr = g0 + CH + tid;
            s_buf[KHALF + CH + tid] = (gr < T_LEN) ? nrow[gr] : 0.f;
        }
        __syncthreads();

        const int l0 = KHALF + tid * EPT;    // LDS idx of this thread's elem 0
        float w = 0.f;
        #pragma unroll
        for (int d = -KHALF; d <= KHALF; ++d) w += s_buf[l0 + d];
        #pragma unroll
        for (int j = 0; j < EPT; ++j) {
            const float nv  = s_buf[l0 + j];
            const float emg = nv - w * inv_k;
            const float tt  = (float)(g0 + tid * EPT + j);
            const bool  inb = (tt >= sf) && (tt < endf);
            float ramped;
            if (tt < head_end)       ramped = (tt - sf) * inv_denom;
            else if (tt >= tail_beg) ramped = (endf - 1.0f - tt) * inv_denom;
            else                     ramped = 1.0f;
            const float m  = inb ? ((ef > 1.0f) ? ramped : 1.0f) : 0.0f;
            const float eb = emg * m;
            sume2 += eb * eb;
            if (j < EPT - 1)
                w += s_buf[l0 + j + KHALF + 1] - s_buf[l0 + j - KHALF];
        }
        __syncthreads();   // done reading before next restage
    }

    // ---- block reduction of sumx2 / sume2 ----
    float v1 = sumx2, v2 = sume2;
    #pragma unroll
    for (int off = 32; off > 0; off >>= 1) {
        v1 += __shfl_down(v1, off, 64);
        v2 += __shfl_down(v2, off, 64);
    }
    const int wave = tid >> 6;
    if ((tid & 63) == 0) { s_red[wave] = v1; s_red[wave + 4] = v2; }
    __syncthreads();
    const float sx = s_red[0] + s_red[1] + s_red[2] + s_red[3];
    const float se = s_red[4] + s_red[5] + s_red[6] + s_red[7];

    const float sig_p = sqrtf(sx / (float)T_LEN) + 1e-8f;
    const float noi_p = sqrtf(se / (float)T_LEN) + 1e-8f;
    const float snr   = 0.5f + snr_u[b] * 2.5f;
    const float coef  = sig_p / (noi_p * snr);

    // ---- Pass 2: recompute emg_b, write out = x + coef*emg_b ----
    for (int ck = 0; ck < NCHUNK; ++ck) {
        const int g0 = ck * CH;
        const float4* nsrc = (const float4*)(nrow + g0);
        float4* sb4 = (float4*)(s_buf + KHALF);
        #pragma unroll
        for (int it = 0; it < F4PT; ++it) {
            int q = tid + it * NTHR;
            sb4[q] = nsrc[q];
        }
        if (tid < KHALF) {
            int gl = g0 - KHALF + tid;
            s_buf[tid] = (gl >= 0) ? nrow[gl] : 0.f;
            int gr = g0 + CH + tid;
            s_buf[KHALF + CH + tid] = (gr < T_LEN) ? nrow[gr] : 0.f;
        }
        __syncthreads();

        const int l0 = KHALF + tid * EPT;
        float w = 0.f;
        #pragma unroll
        for (int d = -KHALF; d <= KHALF; ++d) w += s_buf[l0 + d];
        float e[EPT];
        #pragma unroll
        for (int j = 0; j < EPT; ++j) {
            const float nv  = s_buf[l0 + j];
            const float emg = nv - w * inv_k;
            const float tt  = (float)(g0 + tid * EPT + j);
            const bool  inb = (tt >= sf) && (tt < endf);
            float ramped;
            if (tt < head_end)       ramped = (tt - sf) * inv_denom;
            else if (tt >= tail_beg) ramped = (endf - 1.0f - tt) * inv_denom;
            else                     ramped = 1.0f;
            const float m  = inb ? ((ef > 1.0f) ? ramped : 1.0f) : 0.0f;
            e[j] = emg * m;
            if (j < EPT - 1)
                w += s_buf[l0 + j + KHALF + 1] - s_buf[l0 + j - KHALF];
        }
        __syncthreads();   // all halo reads done -> safe to overwrite

        // write emg_b back over the interior
        #pragma unroll
        for (int j = 0; j < EPT; ++j) s_buf[l0 + j] = e[j];
        __syncthreads();

        // coalesced float4 output for this chunk
        const float4* xsrc = (const float4*)(xrow + g0);
        float4*       odst = (float4*)(orow + g0);
        #pragma unroll
        for (int it = 0; it < F4PT; ++it) {
            int q = tid + it * NTHR;
            float4 ev = sb4[q];
            float4 xv = xsrc[q];
            float4 ov;
            ov.x = xv.x + coef * ev.x;
            ov.y = xv.y + coef * ev.y;
            ov.z = xv.z + coef * ev.z;
            ov.w = xv.w + coef * ev.w;
            odst[q] = ov;
        }
        __syncthreads();   // before next restage
    }
}

extern "C" void kernel_launch(void* const* d_in, const int* in_sizes, int n_in,
                              void* d_out, int out_size, void* d_ws, size_t ws_size,
                              hipStream_t stream) {
    const float* x       = (const float*)d_in[0];
    const float* noise   = (const float*)d_in[1];
    const float* apply_u = (const float*)d_in[2];
    const float* frac_u  = (const float*)d_in[3];
    const float* ch_u    = (const float*)d_in[4];
    const float* burst_u = (const float*)d_in[5];
    const float* start_u = (const float*)d_in[6];
    const float* snr_u   = (const float*)d_in[7];
    float* out = (float*)d_out;

    dim3 grid(B_DIM * C_DIM);
    dim3 block(NTHR);
    emg_inject_kernel<<<grid, block, 0, stream>>>(
        x, noise, apply_u, frac_u, ch_u, burst_u, start_u, snr_u, out);
}

// Round 3
// 134.889 us; speedup vs baseline: 2.0976x; 2.0976x over previous
//
#include <hip/hip_runtime.h>
#include <math.h>

// Problem constants (match reference)
constexpr int T_LEN = 15360;
constexpr int B_DIM = 64;
constexpr int C_DIM = 64;
constexpr int NTHR  = 256;
constexpr int KHALF = 12;                 // k=25 taps -> halo 12
constexpr int SEG    = 12;                // segments per row
constexpr int CH     = T_LEN / SEG;       // 1280 elems / segment
constexpr int EPT    = CH / NTHR;         // 5 elems / thread (odd -> benign LDS stride)
constexpr int F4SEG  = CH / 4;            // 320 float4 / segment

// ---- shared helper: block-uniform affected flag via wave-0 ballot rank ----
__device__ __forceinline__ int compute_affected(const float* __restrict__ ch_u,
                                                const float* __restrict__ frac_u,
                                                const float* __restrict__ apply_u,
                                                int b, int c, int tid, int* s_aff)
{
    if (tid < 64) {
        const float myv = ch_u[(size_t)b * C_DIM + c];
        const float v   = ch_u[(size_t)b * C_DIM + tid];
        const bool pred = (v < myv) || (v == myv && tid < c);
        unsigned long long m = __ballot(pred);
        if (tid == 0) {
            int rank  = (int)__popcll(m);
            int n_aff = (int)floorf(((float)C_DIM * frac_u[b]) * 0.5f);
            if (n_aff < 1) n_aff = 1;
            *s_aff = (apply_u[b] <= 0.4f && rank < n_aff) ? 1 : 0;
        }
    }
    __syncthreads();
    return *s_aff;
}

struct BurstParams {
    float sf, endf, ef, inv_denom, head_end, tail_beg;
};

__device__ __forceinline__ BurstParams burst_params(const float* __restrict__ burst_u,
                                                    const float* __restrict__ start_u,
                                                    int b)
{
    const float bu   = burst_u[b];
    const float bfr  = 0.1f + bu * 0.4f;
    const int   blen = (int)floorf((float)T_LEN * bfr);
    int tmb = T_LEN - blen; if (tmb < 1) tmb = 1;
    const int   start = (int)floorf(start_u[b] * (float)tmb);
    const int   elen  = min(25, blen / 4);
    BurstParams p;
    p.sf   = (float)start;
    p.endf = p.sf + (float)blen;
    p.ef   = (float)elen;
    const float denom = fmaxf(p.ef - 1.0f, 1.0f);
    p.inv_denom = 1.0f / denom;
    p.head_end  = p.sf + p.ef;
    p.tail_beg  = p.endf - p.ef;
    return p;
}

// stage noise segment + halos into s_buf (interior at [KHALF, KHALF+CH))
__device__ __forceinline__ void stage_noise(const float* __restrict__ nrow, int g0,
                                            float* s_buf, int tid)
{
    const float4* nsrc = (const float4*)(nrow + g0);
    float4* sb4 = (float4*)(s_buf + KHALF);   // 48B offset -> 16B aligned
    #pragma unroll
    for (int it = 0; it < 2; ++it) {
        int q = tid + it * NTHR;
        if (q < F4SEG) sb4[q] = nsrc[q];
    }
    if (tid < KHALF) {
        int gl = g0 - KHALF + tid;
        s_buf[tid] = (gl >= 0) ? nrow[gl] : 0.f;
        int gr = g0 + CH + tid;
        s_buf[KHALF + CH + tid] = (gr < T_LEN) ? nrow[gr] : 0.f;
    }
}

// =======================  Kernel A: per-segment stats  =======================
__global__ __launch_bounds__(NTHR, 8)
void emg_stats_kernel(const float* __restrict__ x,
                      const float* __restrict__ noise,
                      const float* __restrict__ apply_u,
                      const float* __restrict__ frac_u,
                      const float* __restrict__ ch_u,
                      const float* __restrict__ burst_u,
                      const float* __restrict__ start_u,
                      float* __restrict__ ws)
{
    const int row = blockIdx.x;
    const int seg = blockIdx.y;
    const int b   = row >> 6;
    const int c   = row & 63;
    const int tid = threadIdx.x;

    __shared__ int   s_aff;
    __shared__ float s_red[8];
    __shared__ __align__(16) float s_buf[CH + 2 * KHALF + 1];

    if (!compute_affected(ch_u, frac_u, apply_u, b, c, tid, &s_aff)) return;

    const BurstParams p = burst_params(burst_u, start_u, b);
    const float inv_k = 1.0f / 25.0f;
    const int g0 = seg * CH;

    // partial sum(x^2) over segment (coalesced float4)
    const float4* x4 = (const float4*)(x + (size_t)row * T_LEN + g0);
    float sumx2 = 0.f;
    #pragma unroll
    for (int it = 0; it < 2; ++it) {
        int q = tid + it * NTHR;
        if (q < F4SEG) {
            float4 xv = x4[q];
            sumx2 += xv.x * xv.x + xv.y * xv.y + xv.z * xv.z + xv.w * xv.w;
        }
    }

    // stage noise + halo, sliding 25-tap window
    const float* nrow = noise + (size_t)row * T_LEN;
    stage_noise(nrow, g0, s_buf, tid);
    __syncthreads();

    const int l0 = KHALF + tid * EPT;
    float w = 0.f;
    #pragma unroll
    for (int d = -KHALF; d <= KHALF; ++d) w += s_buf[l0 + d];
    float sume2 = 0.f;
    #pragma unroll
    for (int j = 0; j < EPT; ++j) {
        const float nv  = s_buf[l0 + j];
        const float emg = nv - w * inv_k;
        const float tt  = (float)(g0 + tid * EPT + j);
        const bool  inb = (tt >= p.sf) && (tt < p.endf);
        float ramped;
        if (tt < p.head_end)       ramped = (tt - p.sf) * p.inv_denom;
        else if (tt >= p.tail_beg) ramped = (p.endf - 1.0f - tt) * p.inv_denom;
        else                       ramped = 1.0f;
        const float m  = inb ? ((p.ef > 1.0f) ? ramped : 1.0f) : 0.0f;
        const float eb = emg * m;
        sume2 += eb * eb;
        if (j < EPT - 1)
            w += s_buf[l0 + j + KHALF + 1] - s_buf[l0 + j - KHALF];
    }

    // block reduction
    float v1 = sumx2, v2 = sume2;
    #pragma unroll
    for (int off = 32; off > 0; off >>= 1) {
        v1 += __shfl_down(v1, off, 64);
        v2 += __shfl_down(v2, off, 64);
    }
    const int wave = tid >> 6;
    if ((tid & 63) == 0) { s_red[wave] = v1; s_red[wave + 4] = v2; }
    __syncthreads();
    if (tid == 0) {
        float sx = s_red[0] + s_red[1] + s_red[2] + s_red[3];
        float se = s_red[4] + s_red[5] + s_red[6] + s_red[7];
        float* wdst = ws + ((size_t)row * SEG + seg) * 2;
        wdst[0] = sx;
        wdst[1] = se;
    }
}

// =======================  Kernel B: apply / copy  =======================
__global__ __launch_bounds__(NTHR, 8)
void emg_apply_kernel(const float* __restrict__ x,
                      const float* __restrict__ noise,
                      const float* __restrict__ apply_u,
                      const float* __restrict__ frac_u,
                      const float* __restrict__ ch_u,
                      const float* __restrict__ burst_u,
                      const float* __restrict__ start_u,
                      const float* __restrict__ snr_u,
                      const float* __restrict__ ws,
                      float* __restrict__ out)
{
    const int row = blockIdx.x;
    const int seg = blockIdx.y;
    const int b   = row >> 6;
    const int c   = row & 63;
    const int tid = threadIdx.x;

    __shared__ int s_aff;
    __shared__ __align__(16) float s_buf[CH + 2 * KHALF + 1];

    const int g0 = seg * CH;
    const float4* x4 = (const float4*)(x   + (size_t)row * T_LEN + g0);
    float4*       o4 = (float4*)      (out + (size_t)row * T_LEN + g0);

    if (!compute_affected(ch_u, frac_u, apply_u, b, c, tid, &s_aff)) {
        // pure copy of this segment
        #pragma unroll
        for (int it = 0; it < 2; ++it) {
            int q = tid + it * NTHR;
            if (q < F4SEG) o4[q] = x4[q];
        }
        return;
    }

    // row sums from per-segment partials (uniform broadcast loads)
    const float* wrow = ws + (size_t)row * SEG * 2;
    float sx = 0.f, se = 0.f;
    #pragma unroll
    for (int s = 0; s < SEG; ++s) { sx += wrow[2 * s]; se += wrow[2 * s + 1]; }

    const float sig_p = sqrtf(sx / (float)T_LEN) + 1e-8f;
    const float noi_p = sqrtf(se / (float)T_LEN) + 1e-8f;
    const float snr   = 0.5f + snr_u[b] * 2.5f;
    const float coef  = sig_p / (noi_p * snr);

    const BurstParams p = burst_params(burst_u, start_u, b);
    const float inv_k = 1.0f / 25.0f;

    const float* nrow = noise + (size_t)row * T_LEN;
    stage_noise(nrow, g0, s_buf, tid);
    __syncthreads();

    const int l0 = KHALF + tid * EPT;
    float w = 0.f;
    #pragma unroll
    for (int d = -KHALF; d <= KHALF; ++d) w += s_buf[l0 + d];
    float e[EPT];
    #pragma unroll
    for (int j = 0; j < EPT; ++j) {
        const float nv  = s_buf[l0 + j];
        const float emg = nv - w * inv_k;
        const float tt  = (float)(g0 + tid * EPT + j);
        const bool  inb = (tt >= p.sf) && (tt < p.endf);
        float ramped;
        if (tt < p.head_end)       ramped = (tt - p.sf) * p.inv_denom;
        else if (tt >= p.tail_beg) ramped = (p.endf - 1.0f - tt) * p.inv_denom;
        else                       ramped = 1.0f;
        const float m  = inb ? ((p.ef > 1.0f) ? ramped : 1.0f) : 0.0f;
        e[j] = emg * m;
        if (j < EPT - 1)
            w += s_buf[l0 + j + KHALF + 1] - s_buf[l0 + j - KHALF];
    }
    __syncthreads();   // all window reads done -> safe to overwrite interior

    #pragma unroll
    for (int j = 0; j < EPT; ++j) s_buf[l0 + j] = e[j];
    __syncthreads();

    // coalesced float4 output: out = x + coef * emg_b
    const float4* sb4 = (const float4*)(s_buf + KHALF);
    #pragma unroll
    for (int it = 0; it < 2; ++it) {
        int q = tid + it * NTHR;
        if (q < F4SEG) {
            float4 ev = sb4[q];
            float4 xv = x4[q];
            float4 ov;
            ov.x = xv.x + coef * ev.x;
            ov.y = xv.y + coef * ev.y;
            ov.z = xv.z + coef * ev.z;
            ov.w = xv.w + coef * ev.w;
            o4[q] = ov;
        }
    }
}

extern "C" void kernel_launch(void* const* d_in, const int* in_sizes, int n_in,
                              void* d_out, int out_size, void* d_ws, size_t ws_size,
                              hipStream_t stream) {
    const float* x       = (const float*)d_in[0];
    const float* noise   = (const float*)d_in[1];
    const float* apply_u = (const float*)d_in[2];
    const float* frac_u  = (const float*)d_in[3];
    const float* ch_u    = (const float*)d_in[4];
    const float* burst_u = (const float*)d_in[5];
    const float* start_u = (const float*)d_in[6];
    const float* snr_u   = (const float*)d_in[7];
    float* out = (float*)d_out;
    float* ws  = (float*)d_ws;   // needs 4096*12*2 floats = 384 KB

    dim3 grid(B_DIM * C_DIM, SEG);
    dim3 block(NTHR);
    emg_stats_kernel<<<grid, block, 0, stream>>>(
        x, noise, apply_u, frac_u, ch_u, burst_u, start_u, ws);
    emg_apply_kernel<<<grid, block, 0, stream>>>(
        x, noise, apply_u, frac_u, ch_u, burst_u, start_u, snr_u, ws, out);
}

// Round 4
// 131.417 us; speedup vs baseline: 2.1530x; 1.0264x over previous
//
#include <hip/hip_runtime.h>
#include <math.h>

// Problem constants (match reference)
constexpr int T_LEN = 15360;
constexpr int B_DIM = 64;
constexpr int C_DIM = 64;
constexpr int NTHR  = 256;
constexpr int KHALF = 12;                 // k=25 taps -> halo 12
constexpr int SEG    = 12;                // segments per row
constexpr int CH     = T_LEN / SEG;       // 1280 elems / segment
constexpr int EPT    = CH / NTHR;         // 5 elems / thread (odd -> benign LDS stride)
constexpr int F4SEG  = CH / 4;            // 320 float4 / segment

// ---- shared helper: block-uniform affected flag via wave-0 ballot rank ----
__device__ __forceinline__ int compute_affected(const float* __restrict__ ch_u,
                                                const float* __restrict__ frac_u,
                                                const float* __restrict__ apply_u,
                                                int b, int c, int tid, int* s_aff)
{
    if (tid < 64) {
        const float myv = ch_u[(size_t)b * C_DIM + c];
        const float v   = ch_u[(size_t)b * C_DIM + tid];
        const bool pred = (v < myv) || (v == myv && tid < c);
        unsigned long long m = __ballot(pred);
        if (tid == 0) {
            int rank  = (int)__popcll(m);
            int n_aff = (int)floorf(((float)C_DIM * frac_u[b]) * 0.5f);
            if (n_aff < 1) n_aff = 1;
            *s_aff = (apply_u[b] <= 0.4f && rank < n_aff) ? 1 : 0;
        }
    }
    __syncthreads();
    return *s_aff;
}

struct BurstParams {
    float sf, endf, ef, inv_denom, head_end, tail_beg;
};

__device__ __forceinline__ BurstParams burst_params(const float* __restrict__ burst_u,
                                                    const float* __restrict__ start_u,
                                                    int b)
{
    const float bu   = burst_u[b];
    const float bfr  = 0.1f + bu * 0.4f;
    const int   blen = (int)floorf((float)T_LEN * bfr);
    int tmb = T_LEN - blen; if (tmb < 1) tmb = 1;
    const int   start = (int)floorf(start_u[b] * (float)tmb);
    const int   elen  = min(25, blen / 4);
    BurstParams p;
    p.sf   = (float)start;
    p.endf = p.sf + (float)blen;
    p.ef   = (float)elen;
    const float denom = fmaxf(p.ef - 1.0f, 1.0f);
    p.inv_denom = 1.0f / denom;
    p.head_end  = p.sf + p.ef;
    p.tail_beg  = p.endf - p.ef;
    return p;
}

// stage noise segment + halos into s_buf (interior at [KHALF, KHALF+CH))
__device__ __forceinline__ void stage_noise(const float* __restrict__ nrow, int g0,
                                            float* s_buf, int tid)
{
    const float4* nsrc = (const float4*)(nrow + g0);
    float4* sb4 = (float4*)(s_buf + KHALF);   // 48B offset -> 16B aligned
    #pragma unroll
    for (int it = 0; it < 2; ++it) {
        int q = tid + it * NTHR;
        if (q < F4SEG) sb4[q] = nsrc[q];
    }
    if (tid < KHALF) {
        int gl = g0 - KHALF + tid;
        s_buf[tid] = (gl >= 0) ? nrow[gl] : 0.f;
        int gr = g0 + CH + tid;
        s_buf[KHALF + CH + tid] = (gr < T_LEN) ? nrow[gr] : 0.f;
    }
}

// ============  Kernel A: bulk copy (unaffected) + per-segment stats  ============
__global__ __launch_bounds__(NTHR, 8)
void emg_bulk_stats_kernel(const float* __restrict__ x,
                           const float* __restrict__ noise,
                           const float* __restrict__ apply_u,
                           const float* __restrict__ frac_u,
                           const float* __restrict__ ch_u,
                           const float* __restrict__ burst_u,
                           const float* __restrict__ start_u,
                           float* __restrict__ ws,
                           float* __restrict__ out)
{
    const int row = blockIdx.x;
    const int seg = blockIdx.y;
    const int b   = row >> 6;
    const int c   = row & 63;
    const int tid = threadIdx.x;

    __shared__ int   s_aff;
    __shared__ float s_red[8];
    __shared__ __align__(16) float s_buf[CH + 2 * KHALF + 1];

    const int g0 = seg * CH;
    const float4* x4 = (const float4*)(x + (size_t)row * T_LEN + g0);

    if (!compute_affected(ch_u, frac_u, apply_u, b, c, tid, &s_aff)) {
        // unaffected: copy this segment out = x (coalesced float4)
        float4* o4 = (float4*)(out + (size_t)row * T_LEN + g0);
        #pragma unroll
        for (int it = 0; it < 2; ++it) {
            int q = tid + it * NTHR;
            if (q < F4SEG) o4[q] = x4[q];
        }
        return;
    }

    const BurstParams p = burst_params(burst_u, start_u, b);
    const float inv_k = 1.0f / 25.0f;

    // partial sum(x^2) over segment (coalesced float4)
    float sumx2 = 0.f;
    #pragma unroll
    for (int it = 0; it < 2; ++it) {
        int q = tid + it * NTHR;
        if (q < F4SEG) {
            float4 xv = x4[q];
            sumx2 += xv.x * xv.x + xv.y * xv.y + xv.z * xv.z + xv.w * xv.w;
        }
    }

    // stage noise + halo, sliding 25-tap window
    const float* nrow = noise + (size_t)row * T_LEN;
    stage_noise(nrow, g0, s_buf, tid);
    __syncthreads();

    const int l0 = KHALF + tid * EPT;
    float w = 0.f;
    #pragma unroll
    for (int d = -KHALF; d <= KHALF; ++d) w += s_buf[l0 + d];
    float sume2 = 0.f;
    #pragma unroll
    for (int j = 0; j < EPT; ++j) {
        const float nv  = s_buf[l0 + j];
        const float emg = nv - w * inv_k;
        const float tt  = (float)(g0 + tid * EPT + j);
        const bool  inb = (tt >= p.sf) && (tt < p.endf);
        float ramped;
        if (tt < p.head_end)       ramped = (tt - p.sf) * p.inv_denom;
        else if (tt >= p.tail_beg) ramped = (p.endf - 1.0f - tt) * p.inv_denom;
        else                       ramped = 1.0f;
        const float m  = inb ? ((p.ef > 1.0f) ? ramped : 1.0f) : 0.0f;
        const float eb = emg * m;
        sume2 += eb * eb;
        if (j < EPT - 1)
            w += s_buf[l0 + j + KHALF + 1] - s_buf[l0 + j - KHALF];
    }

    // block reduction
    float v1 = sumx2, v2 = sume2;
    #pragma unroll
    for (int off = 32; off > 0; off >>= 1) {
        v1 += __shfl_down(v1, off, 64);
        v2 += __shfl_down(v2, off, 64);
    }
    const int wave = tid >> 6;
    if ((tid & 63) == 0) { s_red[wave] = v1; s_red[wave + 4] = v2; }
    __syncthreads();
    if (tid == 0) {
        float sx = s_red[0] + s_red[1] + s_red[2] + s_red[3];
        float se = s_red[4] + s_red[5] + s_red[6] + s_red[7];
        float* wdst = ws + ((size_t)row * SEG + seg) * 2;
        wdst[0] = sx;
        wdst[1] = se;
    }
}

// =======================  Kernel B: apply (affected only)  =======================
__global__ __launch_bounds__(NTHR, 8)
void emg_apply_kernel(const float* __restrict__ x,
                      const float* __restrict__ noise,
                      const float* __restrict__ apply_u,
                      const float* __restrict__ frac_u,
                      const float* __restrict__ ch_u,
                      const float* __restrict__ burst_u,
                      const float* __restrict__ start_u,
                      const float* __restrict__ snr_u,
                      const float* __restrict__ ws,
                      float* __restrict__ out)
{
    const int row = blockIdx.x;
    const int seg = blockIdx.y;
    const int b   = row >> 6;
    const int c   = row & 63;
    const int tid = threadIdx.x;

    __shared__ int s_aff;
    __shared__ __align__(16) float s_buf[CH + 2 * KHALF + 1];

    if (!compute_affected(ch_u, frac_u, apply_u, b, c, tid, &s_aff)) return;

    const int g0 = seg * CH;
    const float4* x4 = (const float4*)(x   + (size_t)row * T_LEN + g0);
    float4*       o4 = (float4*)      (out + (size_t)row * T_LEN + g0);

    // row sums from per-segment partials (uniform broadcast loads, L2-hot)
    const float* wrow = ws + (size_t)row * SEG * 2;
    float sx = 0.f, se = 0.f;
    #pragma unroll
    for (int s = 0; s < SEG; ++s) { sx += wrow[2 * s]; se += wrow[2 * s + 1]; }

    const float sig_p = sqrtf(sx / (float)T_LEN) + 1e-8f;
    const float noi_p = sqrtf(se / (float)T_LEN) + 1e-8f;
    const float snr   = 0.5f + snr_u[b] * 2.5f;
    const float coef  = sig_p / (noi_p * snr);

    const BurstParams p = burst_params(burst_u, start_u, b);
    const float inv_k = 1.0f / 25.0f;

    const float* nrow = noise + (size_t)row * T_LEN;
    stage_noise(nrow, g0, s_buf, tid);
    __syncthreads();

    const int l0 = KHALF + tid * EPT;
    float w = 0.f;
    #pragma unroll
    for (int d = -KHALF; d <= KHALF; ++d) w += s_buf[l0 + d];
    float e[EPT];
    #pragma unroll
    for (int j = 0; j < EPT; ++j) {
        const float nv  = s_buf[l0 + j];
        const float emg = nv - w * inv_k;
        const float tt  = (float)(g0 + tid * EPT + j);
        const bool  inb = (tt >= p.sf) && (tt < p.endf);
        float ramped;
        if (tt < p.head_end)       ramped = (tt - p.sf) * p.inv_denom;
        else if (tt >= p.tail_beg) ramped = (p.endf - 1.0f - tt) * p.inv_denom;
        else                       ramped = 1.0f;
        const float m  = inb ? ((p.ef > 1.0f) ? ramped : 1.0f) : 0.0f;
        e[j] = emg * m;
        if (j < EPT - 1)
            w += s_buf[l0 + j + KHALF + 1] - s_buf[l0 + j - KHALF];
    }
    __syncthreads();   // all window reads done -> safe to overwrite interior

    #pragma unroll
    for (int j = 0; j < EPT; ++j) s_buf[l0 + j] = e[j];
    __syncthreads();

    // coalesced float4 output: out = x + coef * emg_b
    const float4* sb4 = (const float4*)(s_buf + KHALF);
    #pragma unroll
    for (int it = 0; it < 2; ++it) {
        int q = tid + it * NTHR;
        if (q < F4SEG) {
            float4 ev = sb4[q];
            float4 xv = x4[q];
            float4 ov;
            ov.x = xv.x + coef * ev.x;
            ov.y = xv.y + coef * ev.y;
            ov.z = xv.z + coef * ev.z;
            ov.w = xv.w + coef * ev.w;
            o4[q] = ov;
        }
    }
}

extern "C" void kernel_launch(void* const* d_in, const int* in_sizes, int n_in,
                              void* d_out, int out_size, void* d_ws, size_t ws_size,
                              hipStream_t stream) {
    const float* x       = (const float*)d_in[0];
    const float* noise   = (const float*)d_in[1];
    const float* apply_u = (const float*)d_in[2];
    const float* frac_u  = (const float*)d_in[3];
    const float* ch_u    = (const float*)d_in[4];
    const float* burst_u = (const float*)d_in[5];
    const float* start_u = (const float*)d_in[6];
    const float* snr_u   = (const float*)d_in[7];
    float* out = (float*)d_out;
    float* ws  = (float*)d_ws;   // needs 4096*12*2 floats = 384 KB

    dim3 grid(B_DIM * C_DIM, SEG);
    dim3 block(NTHR);
    emg_bulk_stats_kernel<<<grid, block, 0, stream>>>(
        x, noise, apply_u, frac_u, ch_u, burst_u, start_u, ws, out);
    emg_apply_kernel<<<grid, block, 0, stream>>>(
        x, noise, apply_u, frac_u, ch_u, burst_u, start_u, snr_u, ws, out);
}